// Round 14
// baseline (358.541 us; speedup 1.0000x reference)
//
#include <hip/hip_runtime.h>
#include <cstdint>
#include <cstddef>

#pragma clang fp contract(off)

#define N_ANCH 2359296
#define K_PRE  12000
#define K_POST 2000
#define NWORD  188
#define NC     94          // 128-wide chunks
#define TIE_CAP 65536

typedef unsigned int u32;
typedef unsigned long long u64;

__constant__ float c_anch[9][4] = {
  { -84.f,  -40.f,   99.f,   55.f },
  { -176.f, -88.f,  191.f,  103.f },
  { -360.f, -184.f, 375.f,  199.f },
  { -56.f,  -56.f,   71.f,   71.f },
  { -120.f, -120.f, 135.f,  135.f },
  { -248.f, -248.f, 263.f,  263.f },
  { -36.f,  -80.f,   51.f,   95.f },
  { -80.f,  -168.f,  95.f,  183.f },
  { -168.f, -344.f, 183.f,  359.f },
};

// Replica of XLA:CPU GenerateVF32Exp (Cephes/Eigen expf), UNFUSED mul/add.
__device__ __forceinline__ float pexpf(float xin) {
#pragma clang fp contract(off)
  const float exp_hi = 88.3762626647950f;
  const float exp_lo = -88.3762626647949f;
  const float LOG2EF = 1.44269504088896341f;
  const float C1 = 0.693359375f;
  const float C2 = -2.12194440e-4f;
  const float p0 = 1.9875691500E-4f;
  const float p1 = 1.3981999507E-3f;
  const float p2 = 8.3334519073E-3f;
  const float p3 = 4.1665795894E-2f;
  const float p4 = 1.6666665459E-1f;
  const float p5 = 5.0000001201E-1f;
  float x = fminf(fmaxf(xin, exp_lo), exp_hi);
  float fx = floorf(x * LOG2EF + 0.5f);
  float tmp = C1 * fx;
  float z = C2 * fx;
  x = x - tmp;
  x = x - z;
  z = x * x;
  float y = x * p0 + p1;
  y = y * x + p2;
  y = y * x + p3;
  y = y * x + p4;
  y = y * x + p5;
  y = y * z + x;
  y = 1.0f + y;
  int n = (int)fx;
  u32 e = ((u32)(n + 127)) << 23;
  return y * __uint_as_float(e);
}

__device__ __forceinline__ void decode_box(const float* __restrict__ bbox, int aidx,
                                           float4* ob, float* oarea, bool* okeep) {
#pragma clang fp contract(off)
  int pos = aidx / 9;
  int a = aidx - pos * 9;
  int w = pos & 511;
  int h = pos >> 9;
  float shx = (float)(w * 8);
  float shy = (float)(h * 8);
  float ax1 = c_anch[a][0] + shx;
  float ay1 = c_anch[a][1] + shy;
  float ax2 = c_anch[a][2] + shx;
  float ay2 = c_anch[a][3] + shy;
  float aw = (ax2 - ax1) + 1.0f;
  float ah = (ay2 - ay1) + 1.0f;
  float acx = ax1 + 0.5f * aw;
  float acy = ay1 + 0.5f * ah;
  const float* d = bbox + (size_t)pos * 36 + (size_t)a * 4;
  float dx = d[0], dy = d[1], dw = d[2], dh = d[3];
  float pcx = dx * aw + acx;
  float pcy = dy * ah + acy;
  float pw = pexpf(dw) * aw;
  float ph = pexpf(dh) * ah;
  float x1 = pcx - 0.5f * pw;
  float y1 = pcy - 0.5f * ph;
  float x2 = pcx + 0.5f * pw;
  float y2 = pcy + 0.5f * ph;
  x1 = fminf(fmaxf(x1, 0.0f), 4095.0f);
  y1 = fminf(fmaxf(y1, 0.0f), 4095.0f);
  x2 = fminf(fmaxf(x2, 0.0f), 4095.0f);
  y2 = fminf(fmaxf(y2, 0.0f), 4095.0f);
  *ob = make_float4(x1, y1, x2, y2);
  float ww = (x2 - x1) + 1.0f;
  float hh = (y2 - y1) + 1.0f;
  *oarea = ww * hh;
  *okeep = (ww >= 16.0f) && (hh >= 16.0f);
}

// Stage A: keys only; ctl/hist init in block 0; no barriers/atomics.
__global__ void k_scores(const float* __restrict__ cls, const float* __restrict__ bbox,
                         u32* __restrict__ keys, u32* __restrict__ ctl,
                         u32* __restrict__ hist) {
#pragma clang fp contract(off)
  int t = blockIdx.x * blockDim.x + threadIdx.x;
  if (blockIdx.x == 0) {
    if (threadIdx.x < 16) ctl[threadIdx.x] = (threadIdx.x == 1) ? (u32)K_PRE : 0u;
    hist[threadIdx.x] = 0u;
  }
  if (t >= N_ANCH) return;
  int pos = t / 9;
  int a = t - pos * 9;
  float s0 = cls[(size_t)pos * 18 + a];
  float s1 = cls[(size_t)pos * 18 + 9 + a];
  float m = fmaxf(s0, s1);
  float e0 = pexpf(s0 - m);
  float e1 = pexpf(s1 - m);
  float p = e1 / (e0 + e1);
  float4 box; float area; bool km;
  decode_box(bbox, t, &box, &area, &km);
  keys[t] = km ? (__float_as_uint(p) | 0x80000000u) : 0u;
}

// Histogram pass + fused last-block scan. 4-way sub-histograms; grid 256.
__global__ void k_histscan(const u32* __restrict__ keys, u32* __restrict__ ctl,
                           u32* __restrict__ hist, int shift, int pass) {
  __shared__ u32 lh[4][256];
  __shared__ u32 s_last;
  int t = threadIdx.x;
  lh[0][t] = 0u; lh[1][t] = 0u; lh[2][t] = 0u; lh[3][t] = 0u;
  __syncthreads();
  int sub = t & 3;
  u32 prefix = ctl[0];
  u32 msk = (shift == 24) ? 0u : (0xFFFFFFFFu << (shift + 8));
  int stride = gridDim.x * blockDim.x;
  for (int i = blockIdx.x * blockDim.x + t; i < N_ANCH; i += stride) {
    u32 k = keys[i];
    if ((k & msk) == prefix) atomicAdd(&lh[sub][(k >> shift) & 0xFFu], 1u);
  }
  __syncthreads();
  u32 hsum = lh[0][t] + lh[1][t] + lh[2][t] + lh[3][t];
  if (hsum) atomicAdd(&hist[t], hsum);
  __syncthreads();
  if (t == 0) {
    __threadfence();
    u32 old = atomicAdd(&ctl[8 + pass], 1u);
    s_last = (old == gridDim.x - 1) ? 1u : 0u;
  }
  __syncthreads();
  if (!s_last) return;
  __threadfence();
  __shared__ u32 sh[256];
  __shared__ u32 horig[256];
  __shared__ int s_d;
  u32 h = atomicAdd(&hist[t], 0u);   // coherent read (bypass stale L1)
  sh[t] = h; horig[t] = h;
  if (t == 0) s_d = 0;
  u32 krem = ctl[1];
  __syncthreads();
  u32 v = h;
  for (int off = 1; off < 256; off <<= 1) {
    u32 add = (t + off < 256) ? sh[t + off] : 0u;
    __syncthreads();
    v += add;
    sh[t] = v;
    __syncthreads();
  }
  if (sh[t] >= krem) atomicMax(&s_d, t);
  __syncthreads();
  if (t == 0) {
    int d = s_d;
    u32 cum = sh[d] - horig[d];
    ctl[0] |= ((u32)d) << shift;
    ctl[1] = krem - cum;
    if (shift == 0) { ctl[2] = ctl[0]; ctl[3] = ctl[1]; }
  }
  hist[t] = 0u;
}

// Collect winners: per-block LDS staging, ONE global atomic per block.
__global__ void k_collect(const u32* __restrict__ keys, u32* __restrict__ ctl,
                          int* __restrict__ sel, int* __restrict__ tie,
                          u64* __restrict__ comps) {
  __shared__ int stI[2048];
  __shared__ u64 stC[2048];
  __shared__ int stT[256];
  __shared__ u32 s_cnt, s_tcnt, s_base, s_tbase;
  int tid = threadIdx.x;
  if (tid == 0) { s_cnt = 0; s_tcnt = 0; }
  __syncthreads();
  u32 kstar = ctl[2];
  int stride = gridDim.x * blockDim.x;
  for (int i = blockIdx.x * blockDim.x + tid; i < N_ANCH; i += stride) {
    u32 k = keys[i];
    if (k > kstar) {
      u32 p = atomicAdd(&s_cnt, 1u);
      u64 cmp = ((u64)k << 32) | (u64)(0xFFFFFFFFu - (u32)i);
      if (p < 2048u) { stI[p] = i; stC[p] = cmp; }
      else { u32 g = atomicAdd(&ctl[4], 1u); sel[g] = i; comps[g] = cmp; }
    } else if (k == kstar) {
      u32 p = atomicAdd(&s_tcnt, 1u);
      if (p < 256u) stT[p] = i;
      else { u32 g = atomicAdd(&ctl[5], 1u); if (g < TIE_CAP) tie[g] = i; }
    }
  }
  __syncthreads();
  if (tid == 0) {
    u32 n = min(s_cnt, 2048u);
    s_base = atomicAdd(&ctl[4], n);
    u32 tn = min(s_tcnt, 256u);
    s_tbase = atomicAdd(&ctl[5], tn);
  }
  __syncthreads();
  u32 n = min(s_cnt, 2048u);
  for (u32 q = tid; q < n; q += blockDim.x) {
    sel[s_base + q] = stI[q];
    comps[s_base + q] = stC[q];
  }
  u32 tn = min(s_tcnt, 256u);
  for (u32 q = tid; q < tn; q += blockDim.x) {
    u32 g = s_tbase + q;
    if (g < TIE_CAP) tie[g] = stT[q];
  }
}

__global__ void k_tiepick(const u32* __restrict__ ctl, const int* __restrict__ tie,
                          int* __restrict__ sel, u64* __restrict__ comps) {
  u32 T = ctl[5]; if (T > TIE_CAP) T = TIE_CAP;
  if (T > 8192u) T = 8192u;
  u32 need = ctl[3];
  u32 base = ctl[4];
  u32 kstar = ctl[2];
  for (u32 t = threadIdx.x; t < T; t += blockDim.x) {
    int v = tie[t];
    u32 r = 0;
    for (u32 u = 0; u < T; ++u) r += (tie[u] < v) ? 1u : 0u;
    if (r < need) {
      sel[base + r] = v;
      comps[base + r] = ((u64)kstar << 32) | (u64)(0xFFFFFFFFu - (u32)v);
    }
  }
}

// Rank sort v2: comps tiled through LDS (16 KB). Original streamed
// 12000*12000*8B = 1.15 GB through L2 (~33 µs); now global traffic is
// 375 blocks * 96 KB = 36 MB and compares read LDS.
__global__ void k_rankdec(const u64* __restrict__ comps, const int* __restrict__ sel,
                          const float* __restrict__ bbox,
                          float4* __restrict__ props, float* __restrict__ areas) {
  __shared__ u64 tile[2048];
  int tid = threadIdx.x;
  int lane = tid & 63;
  int wave = tid >> 6;
  int base = (blockIdx.x * 4 + wave) * 8;
  u64 c0 = comps[base + 0], c1 = comps[base + 1], c2 = comps[base + 2], c3 = comps[base + 3];
  u64 c4 = comps[base + 4], c5 = comps[base + 5], c6 = comps[base + 6], c7 = comps[base + 7];
  int n0 = 0, n1 = 0, n2 = 0, n3 = 0, n4 = 0, n5 = 0, n6 = 0, n7 = 0;
  for (int t0 = 0; t0 < K_PRE; t0 += 2048) {
    int cnt = min(2048, K_PRE - t0);
    __syncthreads();
    for (int q = tid; q < cnt; q += 256) tile[q] = comps[t0 + q];
    __syncthreads();
    for (int q = lane; q < cnt; q += 64) {
      u64 v = tile[q];
      n0 += (v > c0); n1 += (v > c1); n2 += (v > c2); n3 += (v > c3);
      n4 += (v > c4); n5 += (v > c5); n6 += (v > c6); n7 += (v > c7);
    }
  }
  for (int off = 32; off; off >>= 1) {
    n0 += __shfl_xor(n0, off); n1 += __shfl_xor(n1, off);
    n2 += __shfl_xor(n2, off); n3 += __shfl_xor(n3, off);
    n4 += __shfl_xor(n4, off); n5 += __shfl_xor(n5, off);
    n6 += __shfl_xor(n6, off); n7 += __shfl_xor(n7, off);
  }
  int rk = n0;
  rk = (lane == 1) ? n1 : rk; rk = (lane == 2) ? n2 : rk;
  rk = (lane == 3) ? n3 : rk; rk = (lane == 4) ? n4 : rk;
  rk = (lane == 5) ? n5 : rk; rk = (lane == 6) ? n6 : rk;
  rk = (lane == 7) ? n7 : rk;
  if (lane < 8) {
    float4 box; float area; bool km;
    decode_box(bbox, sel[base + lane], &box, &area, &km);
    props[rk] = box;
    areas[rk] = area;
  }
}

// diag2/sub2 pair layout (R12): entry (chunk c, half h, lane) = words
// {2c,2c+1} (diag) / {2c-2,2c-1} (sub2).
__device__ __forceinline__ int d2idx(int c, int h, int lane) {
  return ((c * 2 + h) * 64 + lane) * 2;
}

// IoU bitmask (R12 regions) with NON-TEMPORAL stores (the isolated k_nms
// experiment): lines land clean in L3 instead of dirty in this XCD's L2,
// so k_nms's far loads avoid remote-dirty probes.
__global__ void k_mask(const float4* __restrict__ props, const float* __restrict__ areas,
                       u64* __restrict__ mask, u64* __restrict__ diag2,
                       u64* __restrict__ sub2) {
#pragma clang fp contract(off)
  int x = blockIdx.x, y = blockIdx.y;
  int cx = x >> 1, cy = y >> 1;
  if (cy + 1 < cx || cy == cx + 1) return;
  __shared__ float4 bj[64];
  __shared__ float aj[64];
  int j0 = y * 64;
  bj[threadIdx.x] = props[j0 + threadIdx.x];
  aj[threadIdx.x] = areas[j0 + threadIdx.x];
  __syncthreads();
  int i = x * 64 + threadIdx.x;
  float4 bi = props[i];
  float ai = areas[i];
  u64 bits = 0;
  for (int jj = 0; jj < 64; ++jj) {
    int j = j0 + jj;
    float4 bb = bj[jj];
    float xx1 = fmaxf(bi.x, bb.x);
    float yy1 = fmaxf(bi.y, bb.y);
    float xx2 = fminf(bi.z, bb.z);
    float yy2 = fminf(bi.w, bb.w);
    float w = fmaxf(0.0f, (xx2 - xx1) + 1.0f);
    float h = fmaxf(0.0f, (yy2 - yy1) + 1.0f);
    float inter = w * h;
    float iou = inter / ((ai + aj[jj]) - inter);
    if ((iou > 0.7f) && (j < K_PRE)) bits |= (1ull << jj);
  }
  if (cy == cx)
    __builtin_nontemporal_store(bits, &diag2[d2idx(cx, x & 1, threadIdx.x) + (y & 1)]);
  else if (cy == cx - 1)
    __builtin_nontemporal_store(bits, &sub2[d2idx(cx, x & 1, threadIdx.x) + (y & 1)]);
  else
    __builtin_nontemporal_store(bits, &mask[(size_t)i * NWORD + y]);
}

// Barrier without vmcnt drain (LDS-only cross-wave comms; in-flight
// global_load_lds stay outstanding across it).
#define NMS_BAR() asm volatile("s_waitcnt lgkmcnt(0)\n\ts_barrier" ::: "memory")

typedef __attribute__((address_space(1))) const u32* gas_p;
typedef __attribute__((address_space(3))) u32* las_p;
__device__ __forceinline__ void gll16(const u64* g, u64* l) {
  __builtin_amdgcn_global_load_lds((gas_p)g, (las_p)l, 16, 0, 0);
}

// Blocked greedy NMS (R12 exact — best measured at 134-135 µs).
__global__ void __launch_bounds__(1024) k_nms(const u64* __restrict__ mask,
                                              const u64* __restrict__ diag2,
                                              const u64* __restrict__ sub2,
                                              const float4* __restrict__ props,
                                              float* __restrict__ out) {
  __shared__ u64 rem[NWORD];
  __shared__ int keepb[K_POST];
  __shared__ int kept[2][128];
  __shared__ u64 dstage[2][2][64][2];   // [par][half][lane][pair]
  __shared__ u64 sstage[2][2][64][2];
  __shared__ int s_kk[2];
  __shared__ int s_nk;
  __shared__ int s_brk;
  int tid = threadIdx.x;
  int lane = tid & 63;
  int wave = tid >> 6;
  for (int w = tid; w < NWORD; w += 1024) {
    int base = w * 64;
    u64 v;
    if (base + 64 <= K_PRE) v = 0ull;
    else if (base >= K_PRE) v = ~0ull;
    else v = (~0ull) << (K_PRE - base);
    rem[w] = v;
  }
  if (tid == 0) { s_nk = 0; s_brk = 0; s_kk[0] = 0; s_kk[1] = 0; }
  if (wave == 0) {
    gll16(diag2 + d2idx(0, 0, lane), &dstage[0][0][0][0]);
    gll16(diag2 + d2idx(0, 1, lane), &dstage[0][1][0][0]);
    gll16(sub2 + d2idx(1, 0, lane), &sstage[1][0][0][0]);
    gll16(sub2 + d2idx(1, 1, lane), &sstage[1][1][0][0]);
  }
  __syncthreads();

  int nk = 0;

  for (int c = 0; c < NC; ++c) {
    if (s_brk) break;
    int par = c & 1;
    if (wave == 0) {
      int cn = min(c + 1, NC - 1);
      int cs = min(c + 2, NC - 1);
      gll16(diag2 + d2idx(cn, 0, lane), &dstage[cn & 1][0][0][0]);
      gll16(diag2 + d2idx(cn, 1, lane), &dstage[cn & 1][1][0][0]);
      gll16(sub2 + d2idx(cs, 0, lane), &sstage[cs & 1][0][0][0]);
      gll16(sub2 + d2idx(cs, 1, lane), &sstage[cs & 1][1][0][0]);
      asm volatile("s_waitcnt vmcnt(4)" ::: "memory");
      u64 dl0A = dstage[par][0][lane][0], dl1A = dstage[par][0][lane][1];
      u64 dh0A = dstage[par][1][lane][0], dh1A = dstage[par][1][lane][1];
      int ps = (c + 1) & 1;
      u64 sl0A = sstage[ps][0][lane][0], sl1A = sstage[ps][0][lane][1];
      u64 sh0A = sstage[ps][1][lane][0], sh1A = sstage[ps][1][lane][1];
      u64 w0 = ~rem[2 * c];
      u64 w1 = ~rem[2 * c + 1];
      u64 km0 = 0, km1 = 0;
      int nk0 = nk;
      while (w0 != 0ull && nk < K_POST) {
        int j = (int)__builtin_ctzll(w0);
        u64 sup = __ballot((int)((dl0A >> j) & 1ull));
        km0 |= (1ull << j);
        nk++;
        w0 &= ~sup;        // includes bit j (diag self-bit always set)
      }
      if (km0) w1 &= ~__ballot((int)((dh0A & km0) != 0ull));  // bulk hi-mask
      while (w1 != 0ull && nk < K_POST) {
        int j = (int)__builtin_ctzll(w1);
        u64 sup = __ballot((int)((dh1A >> j) & 1ull));
        km1 |= (1ull << j);
        nk++;
        w1 &= ~sup;        // includes bit j
      }
      // lane-parallel emit (keeps are in increasing index order)
      int ncnt0 = __popcll(km0);
      u64 below = (1ull << lane) - 1ull;
      if ((km0 >> lane) & 1ull) {
        int pos = nk0 + __popcll(km0 & below);
        int idx = (c << 7) | lane;
        keepb[pos] = idx;
        kept[par][pos - nk0] = idx;
      }
      if ((km1 >> lane) & 1ull) {
        int pos = nk0 + ncnt0 + __popcll(km1 & below);
        int idx = (c << 7) | 64 | lane;
        keepb[pos] = idx;
        kept[par][pos - nk0] = idx;
      }
      if (c + 1 < NC) {
        int plo = (int)((((sl0A & km0) | (sl1A & km1)) != 0ull) ? 1 : 0);
        int phi = (int)((((sh0A & km0) | (sh1A & km1)) != 0ull) ? 1 : 0);
        u64 vlo = __ballot(plo);
        u64 vhi = __ballot(phi);
        if (lane == 0) {
          if (vlo) atomicOr((unsigned long long*)&rem[2 * c + 2], (unsigned long long)vlo);
          if (vhi) atomicOr((unsigned long long*)&rem[2 * c + 3], (unsigned long long)vhi);
        }
      }
      if (lane == 0) { s_kk[par] = nk - nk0; s_nk = nk; s_brk = (nk >= K_POST) ? 1 : 0; }
    } else if (c >= 1) {
      int kkp = s_kk[par ^ 1];
      const int* kb = &kept[par ^ 1][0];
      int wv = wave - 1;              // 0..14
      int seg = wv % 3;               // wave-uniform segment
      int q0 = wv / 3;                // 0..4; rows q0, q0+5, ..., q0+35
      int w = 2 * c + 2 + seg * 64 + lane;
      if (kkp > q0 && w < NWORD) {
        u64 fp0 = 0, fp1 = 0, fp2 = 0, fp3 = 0, fp4 = 0, fp5 = 0, fp6 = 0, fp7 = 0;
        fp0 = mask[(size_t)kb[q0] * NWORD + w];
        if (q0 + 5  < kkp) fp1 = mask[(size_t)kb[q0 + 5]  * NWORD + w];
        if (q0 + 10 < kkp) fp2 = mask[(size_t)kb[q0 + 10] * NWORD + w];
        if (q0 + 15 < kkp) fp3 = mask[(size_t)kb[q0 + 15] * NWORD + w];
        if (q0 + 20 < kkp) fp4 = mask[(size_t)kb[q0 + 20] * NWORD + w];
        if (q0 + 25 < kkp) fp5 = mask[(size_t)kb[q0 + 25] * NWORD + w];
        if (q0 + 30 < kkp) fp6 = mask[(size_t)kb[q0 + 30] * NWORD + w];
        if (q0 + 35 < kkp) fp7 = mask[(size_t)kb[q0 + 35] * NWORD + w];
        u64 v = (fp0 | fp1) | (fp2 | fp3) | ((fp4 | fp5) | (fp6 | fp7));
        for (int q = q0 + 40; q < kkp; q += 5)   // rare overflow
          v |= mask[(size_t)kb[q] * NWORD + w];
        if (v) atomicOr((unsigned long long*)&rem[w], (unsigned long long)v);
      }
    }
    NMS_BAR();
  }
  __syncthreads();
  int fnk = s_nk;
  for (int t = tid; t < K_POST; t += 1024) {
    int kidx = (t < fnk) ? keepb[t] : 0;   // exhausted: argmax over -inf -> 0
    float4 b = props[kidx];
    out[t * 5 + 0] = 0.0f;
    out[t * 5 + 1] = b.x;
    out[t * 5 + 2] = b.y;
    out[t * 5 + 3] = b.z;
    out[t * 5 + 4] = b.w;
  }
}

extern "C" void kernel_launch(void* const* d_in, const int* in_sizes, int n_in,
                              void* d_out, int out_size, void* d_ws, size_t ws_size,
                              hipStream_t stream) {
  const float* cls  = (const float*)d_in[0];
  const float* bbox = (const float*)d_in[1];
  float* out = (float*)d_out;
  char* ws = (char*)d_ws;

  // Layout. mask [0,18096128) overlays keys/ctl/hist/sel/tie (dead before k_mask).
  u64* mask    = (u64*)ws;                      // u64[12032*188]
  u32* keys    = (u32*)ws;                      // [0, 9437184)
  u32* ctl     = (u32*)(ws + 9437184);
  u32* hist    = (u32*)(ws + 9437248);
  int* sel     = (int*)(ws + 9438464);
  int* tie     = (int*)(ws + 9486592);
  u64* comps   = (u64*)(ws + 18096128);         // +96256
  float4* props= (float4*)(ws + 18240512);      // +192512
  float* areas = (float*)(ws + 18433024);       // +48128
  u64* diag2   = (u64*)(ws + 18481152);         // +192512
  u64* sub2    = (u64*)(ws + 18673664);         // +192512 -> 18866176 total

  k_scores<<<dim3((N_ANCH + 255) / 256), dim3(256), 0, stream>>>(cls, bbox, keys, ctl, hist);
  const int shifts[4] = {24, 16, 8, 0};
  for (int s = 0; s < 4; ++s)
    k_histscan<<<dim3(256), dim3(256), 0, stream>>>(keys, ctl, hist, shifts[s], s);
  k_collect<<<dim3(256), dim3(256), 0, stream>>>(keys, ctl, sel, tie, comps);
  k_tiepick<<<dim3(1), dim3(256), 0, stream>>>(ctl, tie, sel, comps);
  k_rankdec<<<dim3(375), dim3(256), 0, stream>>>(comps, sel, bbox, props, areas);
  k_mask<<<dim3(188, 188), dim3(64), 0, stream>>>(props, areas, mask, diag2, sub2);
  k_nms<<<dim3(1), dim3(1024), 0, stream>>>(mask, diag2, sub2, props, out);
}

// Round 15
// 319.281 us; speedup vs baseline: 1.1230x; 1.1230x over previous
//
#include <hip/hip_runtime.h>
#include <cstdint>
#include <cstddef>

#pragma clang fp contract(off)

#define N_ANCH 2359296
#define K_PRE  12000
#define K_POST 2000
#define NWORD  188
#define NC     94          // 128-wide chunks
#define TIE_CAP 65536

typedef unsigned int u32;
typedef unsigned long long u64;

__constant__ float c_anch[9][4] = {
  { -84.f,  -40.f,   99.f,   55.f },
  { -176.f, -88.f,  191.f,  103.f },
  { -360.f, -184.f, 375.f,  199.f },
  { -56.f,  -56.f,   71.f,   71.f },
  { -120.f, -120.f, 135.f,  135.f },
  { -248.f, -248.f, 263.f,  263.f },
  { -36.f,  -80.f,   51.f,   95.f },
  { -80.f,  -168.f,  95.f,  183.f },
  { -168.f, -344.f, 183.f,  359.f },
};

// Replica of XLA:CPU GenerateVF32Exp (Cephes/Eigen expf), UNFUSED mul/add.
__device__ __forceinline__ float pexpf(float xin) {
#pragma clang fp contract(off)
  const float exp_hi = 88.3762626647950f;
  const float exp_lo = -88.3762626647949f;
  const float LOG2EF = 1.44269504088896341f;
  const float C1 = 0.693359375f;
  const float C2 = -2.12194440e-4f;
  const float p0 = 1.9875691500E-4f;
  const float p1 = 1.3981999507E-3f;
  const float p2 = 8.3334519073E-3f;
  const float p3 = 4.1665795894E-2f;
  const float p4 = 1.6666665459E-1f;
  const float p5 = 5.0000001201E-1f;
  float x = fminf(fmaxf(xin, exp_lo), exp_hi);
  float fx = floorf(x * LOG2EF + 0.5f);
  float tmp = C1 * fx;
  float z = C2 * fx;
  x = x - tmp;
  x = x - z;
  z = x * x;
  float y = x * p0 + p1;
  y = y * x + p2;
  y = y * x + p3;
  y = y * x + p4;
  y = y * x + p5;
  y = y * z + x;
  y = 1.0f + y;
  int n = (int)fx;
  u32 e = ((u32)(n + 127)) << 23;
  return y * __uint_as_float(e);
}

__device__ __forceinline__ void decode_box(const float* __restrict__ bbox, int aidx,
                                           float4* ob, float* oarea, bool* okeep) {
#pragma clang fp contract(off)
  int pos = aidx / 9;
  int a = aidx - pos * 9;
  int w = pos & 511;
  int h = pos >> 9;
  float shx = (float)(w * 8);
  float shy = (float)(h * 8);
  float ax1 = c_anch[a][0] + shx;
  float ay1 = c_anch[a][1] + shy;
  float ax2 = c_anch[a][2] + shx;
  float ay2 = c_anch[a][3] + shy;
  float aw = (ax2 - ax1) + 1.0f;
  float ah = (ay2 - ay1) + 1.0f;
  float acx = ax1 + 0.5f * aw;
  float acy = ay1 + 0.5f * ah;
  const float* d = bbox + (size_t)pos * 36 + (size_t)a * 4;
  float dx = d[0], dy = d[1], dw = d[2], dh = d[3];
  float pcx = dx * aw + acx;
  float pcy = dy * ah + acy;
  float pw = pexpf(dw) * aw;
  float ph = pexpf(dh) * ah;
  float x1 = pcx - 0.5f * pw;
  float y1 = pcy - 0.5f * ph;
  float x2 = pcx + 0.5f * pw;
  float y2 = pcy + 0.5f * ph;
  x1 = fminf(fmaxf(x1, 0.0f), 4095.0f);
  y1 = fminf(fmaxf(y1, 0.0f), 4095.0f);
  x2 = fminf(fmaxf(x2, 0.0f), 4095.0f);
  y2 = fminf(fmaxf(y2, 0.0f), 4095.0f);
  *ob = make_float4(x1, y1, x2, y2);
  float ww = (x2 - x1) + 1.0f;
  float hh = (y2 - y1) + 1.0f;
  *oarea = ww * hh;
  *okeep = (ww >= 16.0f) && (hh >= 16.0f);
}

// Stage A: keys only; ctl/hist init in block 0; no barriers/atomics.
__global__ void k_scores(const float* __restrict__ cls, const float* __restrict__ bbox,
                         u32* __restrict__ keys, u32* __restrict__ ctl,
                         u32* __restrict__ hist) {
#pragma clang fp contract(off)
  int t = blockIdx.x * blockDim.x + threadIdx.x;
  if (blockIdx.x == 0) {
    if (threadIdx.x < 16) ctl[threadIdx.x] = (threadIdx.x == 1) ? (u32)K_PRE : 0u;
    hist[threadIdx.x] = 0u;
  }
  if (t >= N_ANCH) return;
  int pos = t / 9;
  int a = t - pos * 9;
  float s0 = cls[(size_t)pos * 18 + a];
  float s1 = cls[(size_t)pos * 18 + 9 + a];
  float m = fmaxf(s0, s1);
  float e0 = pexpf(s0 - m);
  float e1 = pexpf(s1 - m);
  float p = e1 / (e0 + e1);
  float4 box; float area; bool km;
  decode_box(bbox, t, &box, &area, &km);
  keys[t] = km ? (__float_as_uint(p) | 0x80000000u) : 0u;
}

// Histogram pass + fused last-block scan. 4-way sub-histograms; grid 256.
__global__ void k_histscan(const u32* __restrict__ keys, u32* __restrict__ ctl,
                           u32* __restrict__ hist, int shift, int pass) {
  __shared__ u32 lh[4][256];
  __shared__ u32 s_last;
  int t = threadIdx.x;
  lh[0][t] = 0u; lh[1][t] = 0u; lh[2][t] = 0u; lh[3][t] = 0u;
  __syncthreads();
  int sub = t & 3;
  u32 prefix = ctl[0];
  u32 msk = (shift == 24) ? 0u : (0xFFFFFFFFu << (shift + 8));
  int stride = gridDim.x * blockDim.x;
  for (int i = blockIdx.x * blockDim.x + t; i < N_ANCH; i += stride) {
    u32 k = keys[i];
    if ((k & msk) == prefix) atomicAdd(&lh[sub][(k >> shift) & 0xFFu], 1u);
  }
  __syncthreads();
  u32 hsum = lh[0][t] + lh[1][t] + lh[2][t] + lh[3][t];
  if (hsum) atomicAdd(&hist[t], hsum);
  __syncthreads();
  if (t == 0) {
    __threadfence();
    u32 old = atomicAdd(&ctl[8 + pass], 1u);
    s_last = (old == gridDim.x - 1) ? 1u : 0u;
  }
  __syncthreads();
  if (!s_last) return;
  __threadfence();
  __shared__ u32 sh[256];
  __shared__ u32 horig[256];
  __shared__ int s_d;
  u32 h = atomicAdd(&hist[t], 0u);   // coherent read (bypass stale L1)
  sh[t] = h; horig[t] = h;
  if (t == 0) s_d = 0;
  u32 krem = ctl[1];
  __syncthreads();
  u32 v = h;
  for (int off = 1; off < 256; off <<= 1) {
    u32 add = (t + off < 256) ? sh[t + off] : 0u;
    __syncthreads();
    v += add;
    sh[t] = v;
    __syncthreads();
  }
  if (sh[t] >= krem) atomicMax(&s_d, t);
  __syncthreads();
  if (t == 0) {
    int d = s_d;
    u32 cum = sh[d] - horig[d];
    ctl[0] |= ((u32)d) << shift;
    ctl[1] = krem - cum;
    if (shift == 0) { ctl[2] = ctl[0]; ctl[3] = ctl[1]; }
  }
  hist[t] = 0u;
}

// Collect winners: per-block LDS staging, ONE global atomic per block.
__global__ void k_collect(const u32* __restrict__ keys, u32* __restrict__ ctl,
                          int* __restrict__ sel, int* __restrict__ tie,
                          u64* __restrict__ comps) {
  __shared__ int stI[2048];
  __shared__ u64 stC[2048];
  __shared__ int stT[256];
  __shared__ u32 s_cnt, s_tcnt, s_base, s_tbase;
  int tid = threadIdx.x;
  if (tid == 0) { s_cnt = 0; s_tcnt = 0; }
  __syncthreads();
  u32 kstar = ctl[2];
  int stride = gridDim.x * blockDim.x;
  for (int i = blockIdx.x * blockDim.x + tid; i < N_ANCH; i += stride) {
    u32 k = keys[i];
    if (k > kstar) {
      u32 p = atomicAdd(&s_cnt, 1u);
      u64 cmp = ((u64)k << 32) | (u64)(0xFFFFFFFFu - (u32)i);
      if (p < 2048u) { stI[p] = i; stC[p] = cmp; }
      else { u32 g = atomicAdd(&ctl[4], 1u); sel[g] = i; comps[g] = cmp; }
    } else if (k == kstar) {
      u32 p = atomicAdd(&s_tcnt, 1u);
      if (p < 256u) stT[p] = i;
      else { u32 g = atomicAdd(&ctl[5], 1u); if (g < TIE_CAP) tie[g] = i; }
    }
  }
  __syncthreads();
  if (tid == 0) {
    u32 n = min(s_cnt, 2048u);
    s_base = atomicAdd(&ctl[4], n);
    u32 tn = min(s_tcnt, 256u);
    s_tbase = atomicAdd(&ctl[5], tn);
  }
  __syncthreads();
  u32 n = min(s_cnt, 2048u);
  for (u32 q = tid; q < n; q += blockDim.x) {
    sel[s_base + q] = stI[q];
    comps[s_base + q] = stC[q];
  }
  u32 tn = min(s_tcnt, 256u);
  for (u32 q = tid; q < tn; q += blockDim.x) {
    u32 g = s_tbase + q;
    if (g < TIE_CAP) tie[g] = stT[q];
  }
}

__global__ void k_tiepick(const u32* __restrict__ ctl, const int* __restrict__ tie,
                          int* __restrict__ sel, u64* __restrict__ comps) {
  u32 T = ctl[5]; if (T > TIE_CAP) T = TIE_CAP;
  if (T > 8192u) T = 8192u;
  u32 need = ctl[3];
  u32 base = ctl[4];
  u32 kstar = ctl[2];
  for (u32 t = threadIdx.x; t < T; t += blockDim.x) {
    int v = tie[t];
    u32 r = 0;
    for (u32 u = 0; u < T; ++u) r += (tie[u] < v) ? 1u : 0u;
    if (r < need) {
      sel[base + r] = v;
      comps[base + r] = ((u64)kstar << 32) | (u64)(0xFFFFFFFFu - (u32)v);
    }
  }
}

// Rank sort: comps tiled through LDS (neutral vs streaming — comps is
// L2-resident — but no worse; kept).
__global__ void k_rankdec(const u64* __restrict__ comps, const int* __restrict__ sel,
                          const float* __restrict__ bbox,
                          float4* __restrict__ props, float* __restrict__ areas) {
  __shared__ u64 tile[2048];
  int tid = threadIdx.x;
  int lane = tid & 63;
  int wave = tid >> 6;
  int base = (blockIdx.x * 4 + wave) * 8;
  u64 c0 = comps[base + 0], c1 = comps[base + 1], c2 = comps[base + 2], c3 = comps[base + 3];
  u64 c4 = comps[base + 4], c5 = comps[base + 5], c6 = comps[base + 6], c7 = comps[base + 7];
  int n0 = 0, n1 = 0, n2 = 0, n3 = 0, n4 = 0, n5 = 0, n6 = 0, n7 = 0;
  for (int t0 = 0; t0 < K_PRE; t0 += 2048) {
    int cnt = min(2048, K_PRE - t0);
    __syncthreads();
    for (int q = tid; q < cnt; q += 256) tile[q] = comps[t0 + q];
    __syncthreads();
    for (int q = lane; q < cnt; q += 64) {
      u64 v = tile[q];
      n0 += (v > c0); n1 += (v > c1); n2 += (v > c2); n3 += (v > c3);
      n4 += (v > c4); n5 += (v > c5); n6 += (v > c6); n7 += (v > c7);
    }
  }
  for (int off = 32; off; off >>= 1) {
    n0 += __shfl_xor(n0, off); n1 += __shfl_xor(n1, off);
    n2 += __shfl_xor(n2, off); n3 += __shfl_xor(n3, off);
    n4 += __shfl_xor(n4, off); n5 += __shfl_xor(n5, off);
    n6 += __shfl_xor(n6, off); n7 += __shfl_xor(n7, off);
  }
  int rk = n0;
  rk = (lane == 1) ? n1 : rk; rk = (lane == 2) ? n2 : rk;
  rk = (lane == 3) ? n3 : rk; rk = (lane == 4) ? n4 : rk;
  rk = (lane == 5) ? n5 : rk; rk = (lane == 6) ? n6 : rk;
  rk = (lane == 7) ? n7 : rk;
  if (lane < 8) {
    float4 box; float area; bool km;
    decode_box(bbox, sel[base + lane], &box, &area, &km);
    props[rk] = box;
    areas[rk] = area;
  }
}

// diag2/sub2 pair layout (R12): entry (chunk c, half h, lane) = words
// {2c,2c+1} (diag) / {2c-2,2c-1} (sub2).
__device__ __forceinline__ int d2idx(int c, int h, int lane) {
  return ((c * 2 + h) * 64 + lane) * 2;
}

// IoU bitmask (R12 regions, PLAIN stores — NT stores cost +40 µs in k_nms, R14).
__global__ void k_mask(const float4* __restrict__ props, const float* __restrict__ areas,
                       u64* __restrict__ mask, u64* __restrict__ diag2,
                       u64* __restrict__ sub2) {
#pragma clang fp contract(off)
  int x = blockIdx.x, y = blockIdx.y;
  int cx = x >> 1, cy = y >> 1;
  if (cy + 1 < cx || cy == cx + 1) return;
  __shared__ float4 bj[64];
  __shared__ float aj[64];
  int j0 = y * 64;
  bj[threadIdx.x] = props[j0 + threadIdx.x];
  aj[threadIdx.x] = areas[j0 + threadIdx.x];
  __syncthreads();
  int i = x * 64 + threadIdx.x;
  float4 bi = props[i];
  float ai = areas[i];
  u64 bits = 0;
  for (int jj = 0; jj < 64; ++jj) {
    int j = j0 + jj;
    float4 bb = bj[jj];
    float xx1 = fmaxf(bi.x, bb.x);
    float yy1 = fmaxf(bi.y, bb.y);
    float xx2 = fminf(bi.z, bb.z);
    float yy2 = fminf(bi.w, bb.w);
    float w = fmaxf(0.0f, (xx2 - xx1) + 1.0f);
    float h = fmaxf(0.0f, (yy2 - yy1) + 1.0f);
    float inter = w * h;
    float iou = inter / ((ai + aj[jj]) - inter);
    if ((iou > 0.7f) && (j < K_PRE)) bits |= (1ull << jj);
  }
  if (cy == cx)          diag2[d2idx(cx, x & 1, threadIdx.x) + (y & 1)] = bits;
  else if (cy == cx - 1) sub2[d2idx(cx, x & 1, threadIdx.x) + (y & 1)] = bits;
  else                   mask[(size_t)i * NWORD + y] = bits;
}

// Barrier without vmcnt drain (LDS-only cross-wave comms; in-flight
// global_load_lds stay outstanding across it).
#define NMS_BAR() asm volatile("s_waitcnt lgkmcnt(0)\n\ts_barrier" ::: "memory")

typedef __attribute__((address_space(1))) const u32* gas_p;
typedef __attribute__((address_space(3))) u32* las_p;
__device__ __forceinline__ void gll16(const u64* g, u64* l) {
  __builtin_amdgcn_global_load_lds((gas_p)g, (las_p)l, 16, 0, 0);
}

// Blocked greedy NMS v15 = R12 + DE-BRANCHED far batch.
// R14's VGPR=24 proved the 8-load far "batch" was serialized: each load sat
// behind its own `if (q0+5i < kkp)` branch and the register budget couldn't
// hold 8 in-flight loads. Fix: unconditional clamped indices (duplicates
// benign under OR), no control flow between the 8 LDS reads and 8 global
// loads; launch_bounds(1024,1) frees the register file.
__global__ void __launch_bounds__(1024, 1) k_nms(const u64* __restrict__ mask,
                                                 const u64* __restrict__ diag2,
                                                 const u64* __restrict__ sub2,
                                                 const float4* __restrict__ props,
                                                 float* __restrict__ out) {
  __shared__ u64 rem[NWORD];
  __shared__ int keepb[K_POST];
  __shared__ int kept[2][128];
  __shared__ u64 dstage[2][2][64][2];   // [par][half][lane][pair]
  __shared__ u64 sstage[2][2][64][2];
  __shared__ int s_kk[2];
  __shared__ int s_nk;
  __shared__ int s_brk;
  int tid = threadIdx.x;
  int lane = tid & 63;
  int wave = tid >> 6;
  for (int w = tid; w < NWORD; w += 1024) {
    int base = w * 64;
    u64 v;
    if (base + 64 <= K_PRE) v = 0ull;
    else if (base >= K_PRE) v = ~0ull;
    else v = (~0ull) << (K_PRE - base);
    rem[w] = v;
  }
  if (tid == 0) { s_nk = 0; s_brk = 0; s_kk[0] = 0; s_kk[1] = 0; }
  if (wave == 0) {
    gll16(diag2 + d2idx(0, 0, lane), &dstage[0][0][0][0]);
    gll16(diag2 + d2idx(0, 1, lane), &dstage[0][1][0][0]);
    gll16(sub2 + d2idx(1, 0, lane), &sstage[1][0][0][0]);
    gll16(sub2 + d2idx(1, 1, lane), &sstage[1][1][0][0]);
  }
  __syncthreads();

  int nk = 0;

  for (int c = 0; c < NC; ++c) {
    if (s_brk) break;
    int par = c & 1;
    if (wave == 0) {
      int cn = min(c + 1, NC - 1);
      int cs = min(c + 2, NC - 1);
      gll16(diag2 + d2idx(cn, 0, lane), &dstage[cn & 1][0][0][0]);
      gll16(diag2 + d2idx(cn, 1, lane), &dstage[cn & 1][1][0][0]);
      gll16(sub2 + d2idx(cs, 0, lane), &sstage[cs & 1][0][0][0]);
      gll16(sub2 + d2idx(cs, 1, lane), &sstage[cs & 1][1][0][0]);
      asm volatile("s_waitcnt vmcnt(4)" ::: "memory");
      u64 dl0A = dstage[par][0][lane][0], dl1A = dstage[par][0][lane][1];
      u64 dh0A = dstage[par][1][lane][0], dh1A = dstage[par][1][lane][1];
      int ps = (c + 1) & 1;
      u64 sl0A = sstage[ps][0][lane][0], sl1A = sstage[ps][0][lane][1];
      u64 sh0A = sstage[ps][1][lane][0], sh1A = sstage[ps][1][lane][1];
      u64 w0 = ~rem[2 * c];
      u64 w1 = ~rem[2 * c + 1];
      u64 km0 = 0, km1 = 0;
      int nk0 = nk;
      while (w0 != 0ull && nk < K_POST) {
        int j = (int)__builtin_ctzll(w0);
        u64 sup = __ballot((int)((dl0A >> j) & 1ull));
        km0 |= (1ull << j);
        nk++;
        w0 &= ~sup;        // includes bit j (diag self-bit always set)
      }
      if (km0) w1 &= ~__ballot((int)((dh0A & km0) != 0ull));  // bulk hi-mask
      while (w1 != 0ull && nk < K_POST) {
        int j = (int)__builtin_ctzll(w1);
        u64 sup = __ballot((int)((dh1A >> j) & 1ull));
        km1 |= (1ull << j);
        nk++;
        w1 &= ~sup;        // includes bit j
      }
      // lane-parallel emit (keeps are in increasing index order)
      int ncnt0 = __popcll(km0);
      u64 below = (1ull << lane) - 1ull;
      if ((km0 >> lane) & 1ull) {
        int pos = nk0 + __popcll(km0 & below);
        int idx = (c << 7) | lane;
        keepb[pos] = idx;
        kept[par][pos - nk0] = idx;
      }
      if ((km1 >> lane) & 1ull) {
        int pos = nk0 + ncnt0 + __popcll(km1 & below);
        int idx = (c << 7) | 64 | lane;
        keepb[pos] = idx;
        kept[par][pos - nk0] = idx;
      }
      if (c + 1 < NC) {
        int plo = (int)((((sl0A & km0) | (sl1A & km1)) != 0ull) ? 1 : 0);
        int phi = (int)((((sh0A & km0) | (sh1A & km1)) != 0ull) ? 1 : 0);
        u64 vlo = __ballot(plo);
        u64 vhi = __ballot(phi);
        if (lane == 0) {
          if (vlo) atomicOr((unsigned long long*)&rem[2 * c + 2], (unsigned long long)vlo);
          if (vhi) atomicOr((unsigned long long*)&rem[2 * c + 3], (unsigned long long)vhi);
        }
      }
      if (lane == 0) { s_kk[par] = nk - nk0; s_nk = nk; s_brk = (nk >= K_POST) ? 1 : 0; }
    } else if (c >= 1) {
      int kkp = s_kk[par ^ 1];
      const int* kb = &kept[par ^ 1][0];
      int wv = wave - 1;              // 0..14
      int seg = wv % 3;               // wave-uniform segment
      int q0 = wv / 3;                // 0..4; rows q0, q0+5, ..., q0+35
      int w = 2 * c + 2 + seg * 64 + lane;
      if (kkp > q0 && w < NWORD) {
        int m = kkp - 1;
        // unconditional clamped batch: 8 LDS reads, then 8 global loads,
        // no branches in between -> all 8 loads share one latency window.
        int i0 = kb[q0];
        int i1 = kb[min(q0 + 5, m)];
        int i2 = kb[min(q0 + 10, m)];
        int i3 = kb[min(q0 + 15, m)];
        int i4 = kb[min(q0 + 20, m)];
        int i5 = kb[min(q0 + 25, m)];
        int i6 = kb[min(q0 + 30, m)];
        int i7 = kb[min(q0 + 35, m)];
        u64 fp0 = mask[(size_t)i0 * NWORD + w];
        u64 fp1 = mask[(size_t)i1 * NWORD + w];
        u64 fp2 = mask[(size_t)i2 * NWORD + w];
        u64 fp3 = mask[(size_t)i3 * NWORD + w];
        u64 fp4 = mask[(size_t)i4 * NWORD + w];
        u64 fp5 = mask[(size_t)i5 * NWORD + w];
        u64 fp6 = mask[(size_t)i6 * NWORD + w];
        u64 fp7 = mask[(size_t)i7 * NWORD + w];
        u64 v = (fp0 | fp1) | (fp2 | fp3) | ((fp4 | fp5) | (fp6 | fp7));
        for (int q = q0 + 40; q < kkp; q += 5)   // rare overflow
          v |= mask[(size_t)kb[q] * NWORD + w];
        if (v) atomicOr((unsigned long long*)&rem[w], (unsigned long long)v);
      }
    }
    NMS_BAR();
  }
  __syncthreads();
  int fnk = s_nk;
  for (int t = tid; t < K_POST; t += 1024) {
    int kidx = (t < fnk) ? keepb[t] : 0;   // exhausted: argmax over -inf -> 0
    float4 b = props[kidx];
    out[t * 5 + 0] = 0.0f;
    out[t * 5 + 1] = b.x;
    out[t * 5 + 2] = b.y;
    out[t * 5 + 3] = b.z;
    out[t * 5 + 4] = b.w;
  }
}

extern "C" void kernel_launch(void* const* d_in, const int* in_sizes, int n_in,
                              void* d_out, int out_size, void* d_ws, size_t ws_size,
                              hipStream_t stream) {
  const float* cls  = (const float*)d_in[0];
  const float* bbox = (const float*)d_in[1];
  float* out = (float*)d_out;
  char* ws = (char*)d_ws;

  // Layout. mask [0,18096128) overlays keys/ctl/hist/sel/tie (dead before k_mask).
  u64* mask    = (u64*)ws;                      // u64[12032*188]
  u32* keys    = (u32*)ws;                      // [0, 9437184)
  u32* ctl     = (u32*)(ws + 9437184);
  u32* hist    = (u32*)(ws + 9437248);
  int* sel     = (int*)(ws + 9438464);
  int* tie     = (int*)(ws + 9486592);
  u64* comps   = (u64*)(ws + 18096128);         // +96256
  float4* props= (float4*)(ws + 18240512);      // +192512
  float* areas = (float*)(ws + 18433024);       // +48128
  u64* diag2   = (u64*)(ws + 18481152);         // +192512
  u64* sub2    = (u64*)(ws + 18673664);         // +192512 -> 18866176 total

  k_scores<<<dim3((N_ANCH + 255) / 256), dim3(256), 0, stream>>>(cls, bbox, keys, ctl, hist);
  const int shifts[4] = {24, 16, 8, 0};
  for (int s = 0; s < 4; ++s)
    k_histscan<<<dim3(256), dim3(256), 0, stream>>>(keys, ctl, hist, shifts[s], s);
  k_collect<<<dim3(256), dim3(256), 0, stream>>>(keys, ctl, sel, tie, comps);
  k_tiepick<<<dim3(1), dim3(256), 0, stream>>>(ctl, tie, sel, comps);
  k_rankdec<<<dim3(375), dim3(256), 0, stream>>>(comps, sel, bbox, props, areas);
  k_mask<<<dim3(188, 188), dim3(64), 0, stream>>>(props, areas, mask, diag2, sub2);
  k_nms<<<dim3(1), dim3(1024), 0, stream>>>(mask, diag2, sub2, props, out);
}

// Round 16
// 304.731 us; speedup vs baseline: 1.1766x; 1.0477x over previous
//
#include <hip/hip_runtime.h>
#include <cstdint>
#include <cstddef>

#pragma clang fp contract(off)

#define N_ANCH 2359296
#define K_PRE  12000
#define K_POST 2000
#define NWORD  188
#define NC     94          // 128-wide chunks
#define TIE_CAP 65536

typedef unsigned int u32;
typedef unsigned long long u64;

__constant__ float c_anch[9][4] = {
  { -84.f,  -40.f,   99.f,   55.f },
  { -176.f, -88.f,  191.f,  103.f },
  { -360.f, -184.f, 375.f,  199.f },
  { -56.f,  -56.f,   71.f,   71.f },
  { -120.f, -120.f, 135.f,  135.f },
  { -248.f, -248.f, 263.f,  263.f },
  { -36.f,  -80.f,   51.f,   95.f },
  { -80.f,  -168.f,  95.f,  183.f },
  { -168.f, -344.f, 183.f,  359.f },
};

// Replica of XLA:CPU GenerateVF32Exp (Cephes/Eigen expf), UNFUSED mul/add.
__device__ __forceinline__ float pexpf(float xin) {
#pragma clang fp contract(off)
  const float exp_hi = 88.3762626647950f;
  const float exp_lo = -88.3762626647949f;
  const float LOG2EF = 1.44269504088896341f;
  const float C1 = 0.693359375f;
  const float C2 = -2.12194440e-4f;
  const float p0 = 1.9875691500E-4f;
  const float p1 = 1.3981999507E-3f;
  const float p2 = 8.3334519073E-3f;
  const float p3 = 4.1665795894E-2f;
  const float p4 = 1.6666665459E-1f;
  const float p5 = 5.0000001201E-1f;
  float x = fminf(fmaxf(xin, exp_lo), exp_hi);
  float fx = floorf(x * LOG2EF + 0.5f);
  float tmp = C1 * fx;
  float z = C2 * fx;
  x = x - tmp;
  x = x - z;
  z = x * x;
  float y = x * p0 + p1;
  y = y * x + p2;
  y = y * x + p3;
  y = y * x + p4;
  y = y * x + p5;
  y = y * z + x;
  y = 1.0f + y;
  int n = (int)fx;
  u32 e = ((u32)(n + 127)) << 23;
  return y * __uint_as_float(e);
}

__device__ __forceinline__ void decode_box(const float* __restrict__ bbox, int aidx,
                                           float4* ob, float* oarea, bool* okeep) {
#pragma clang fp contract(off)
  int pos = aidx / 9;
  int a = aidx - pos * 9;
  int w = pos & 511;
  int h = pos >> 9;
  float shx = (float)(w * 8);
  float shy = (float)(h * 8);
  float ax1 = c_anch[a][0] + shx;
  float ay1 = c_anch[a][1] + shy;
  float ax2 = c_anch[a][2] + shx;
  float ay2 = c_anch[a][3] + shy;
  float aw = (ax2 - ax1) + 1.0f;
  float ah = (ay2 - ay1) + 1.0f;
  float acx = ax1 + 0.5f * aw;
  float acy = ay1 + 0.5f * ah;
  const float* d = bbox + (size_t)pos * 36 + (size_t)a * 4;
  float dx = d[0], dy = d[1], dw = d[2], dh = d[3];
  float pcx = dx * aw + acx;
  float pcy = dy * ah + acy;
  float pw = pexpf(dw) * aw;
  float ph = pexpf(dh) * ah;
  float x1 = pcx - 0.5f * pw;
  float y1 = pcy - 0.5f * ph;
  float x2 = pcx + 0.5f * pw;
  float y2 = pcy + 0.5f * ph;
  x1 = fminf(fmaxf(x1, 0.0f), 4095.0f);
  y1 = fminf(fmaxf(y1, 0.0f), 4095.0f);
  x2 = fminf(fmaxf(x2, 0.0f), 4095.0f);
  y2 = fminf(fmaxf(y2, 0.0f), 4095.0f);
  *ob = make_float4(x1, y1, x2, y2);
  float ww = (x2 - x1) + 1.0f;
  float hh = (y2 - y1) + 1.0f;
  *oarea = ww * hh;
  *okeep = (ww >= 16.0f) && (hh >= 16.0f);
}

// Stage A: keys only; ctl/hist init in block 0; no barriers/atomics.
__global__ void k_scores(const float* __restrict__ cls, const float* __restrict__ bbox,
                         u32* __restrict__ keys, u32* __restrict__ ctl,
                         u32* __restrict__ hist) {
#pragma clang fp contract(off)
  int t = blockIdx.x * blockDim.x + threadIdx.x;
  if (blockIdx.x == 0) {
    if (threadIdx.x < 16) ctl[threadIdx.x] = (threadIdx.x == 1) ? (u32)K_PRE : 0u;
    if (threadIdx.x < 256) hist[threadIdx.x] = 0u;
  }
  if (t >= N_ANCH) return;
  int pos = t / 9;
  int a = t - pos * 9;
  float s0 = cls[(size_t)pos * 18 + a];
  float s1 = cls[(size_t)pos * 18 + 9 + a];
  float m = fmaxf(s0, s1);
  float e0 = pexpf(s0 - m);
  float e1 = pexpf(s1 - m);
  float p = e1 / (e0 + e1);
  float4 box; float area; bool km;
  decode_box(bbox, t, &box, &area, &km);
  keys[t] = km ? (__float_as_uint(p) | 0x80000000u) : 0u;
}

// Histogram pass + fused last-block scan. 1024 threads (4 waves/SIMD for
// latency hiding on the streaming scan); grid stays 256 (low ctl cascade).
__global__ void __launch_bounds__(1024) k_histscan(const u32* __restrict__ keys,
                                                   u32* __restrict__ ctl,
                                                   u32* __restrict__ hist,
                                                   int shift, int pass) {
  __shared__ u32 lh[4][256];
  __shared__ u32 s_last;
  int t = threadIdx.x;
  if (t < 256) { lh[0][t] = 0u; lh[1][t] = 0u; lh[2][t] = 0u; lh[3][t] = 0u; }
  __syncthreads();
  int sub = t & 3;
  u32 prefix = ctl[0];
  u32 msk = (shift == 24) ? 0u : (0xFFFFFFFFu << (shift + 8));
  int stride = gridDim.x * blockDim.x;
  for (int i = blockIdx.x * blockDim.x + t; i < N_ANCH; i += stride) {
    u32 k = keys[i];
    if ((k & msk) == prefix) atomicAdd(&lh[sub][(k >> shift) & 0xFFu], 1u);
  }
  __syncthreads();
  if (t < 256) {
    u32 hsum = lh[0][t] + lh[1][t] + lh[2][t] + lh[3][t];
    if (hsum) atomicAdd(&hist[t], hsum);
  }
  __syncthreads();
  if (t == 0) {
    __threadfence();
    u32 old = atomicAdd(&ctl[8 + pass], 1u);
    s_last = (old == gridDim.x - 1) ? 1u : 0u;
  }
  __syncthreads();
  if (!s_last) return;
  __threadfence();
  __shared__ u32 sh[256];
  __shared__ u32 horig[256];
  __shared__ int s_d;
  u32 h = 0;
  if (t < 256) {
    h = atomicAdd(&hist[t], 0u);   // coherent read (bypass stale L1)
    sh[t] = h; horig[t] = h;
  }
  if (t == 0) s_d = 0;
  u32 krem = ctl[1];
  __syncthreads();
  u32 v = h;
  for (int off = 1; off < 256; off <<= 1) {
    u32 add = (t < 256 && t + off < 256) ? sh[t + off] : 0u;
    __syncthreads();
    if (t < 256) { v += add; sh[t] = v; }
    __syncthreads();
  }
  if (t < 256 && sh[t] >= krem) atomicMax(&s_d, t);
  __syncthreads();
  if (t == 0) {
    int d = s_d;
    u32 cum = sh[d] - horig[d];
    ctl[0] |= ((u32)d) << shift;
    ctl[1] = krem - cum;
    if (shift == 0) { ctl[2] = ctl[0]; ctl[3] = ctl[1]; }
  }
  if (t < 256) hist[t] = 0u;
}

// Collect winners: per-block LDS staging, ONE global atomic per block.
// 1024 threads (latency hiding), grid 256.
__global__ void __launch_bounds__(1024) k_collect(const u32* __restrict__ keys,
                                                  u32* __restrict__ ctl,
                                                  int* __restrict__ sel,
                                                  int* __restrict__ tie,
                                                  u64* __restrict__ comps) {
  __shared__ int stI[2048];
  __shared__ u64 stC[2048];
  __shared__ int stT[256];
  __shared__ u32 s_cnt, s_tcnt, s_base, s_tbase;
  int tid = threadIdx.x;
  if (tid == 0) { s_cnt = 0; s_tcnt = 0; }
  __syncthreads();
  u32 kstar = ctl[2];
  int stride = gridDim.x * blockDim.x;
  for (int i = blockIdx.x * blockDim.x + tid; i < N_ANCH; i += stride) {
    u32 k = keys[i];
    if (k > kstar) {
      u32 p = atomicAdd(&s_cnt, 1u);
      u64 cmp = ((u64)k << 32) | (u64)(0xFFFFFFFFu - (u32)i);
      if (p < 2048u) { stI[p] = i; stC[p] = cmp; }
      else { u32 g = atomicAdd(&ctl[4], 1u); sel[g] = i; comps[g] = cmp; }
    } else if (k == kstar) {
      u32 p = atomicAdd(&s_tcnt, 1u);
      if (p < 256u) stT[p] = i;
      else { u32 g = atomicAdd(&ctl[5], 1u); if (g < TIE_CAP) tie[g] = i; }
    }
  }
  __syncthreads();
  if (tid == 0) {
    u32 n = min(s_cnt, 2048u);
    s_base = atomicAdd(&ctl[4], n);
    u32 tn = min(s_tcnt, 256u);
    s_tbase = atomicAdd(&ctl[5], tn);
  }
  __syncthreads();
  u32 n = min(s_cnt, 2048u);
  for (u32 q = tid; q < n; q += blockDim.x) {
    sel[s_base + q] = stI[q];
    comps[s_base + q] = stC[q];
  }
  u32 tn = min(s_tcnt, 256u);
  for (u32 q = tid; q < tn; q += blockDim.x) {
    u32 g = s_tbase + q;
    if (g < TIE_CAP) tie[g] = stT[q];
  }
}

__global__ void k_tiepick(const u32* __restrict__ ctl, const int* __restrict__ tie,
                          int* __restrict__ sel, u64* __restrict__ comps) {
  u32 T = ctl[5]; if (T > TIE_CAP) T = TIE_CAP;
  if (T > 8192u) T = 8192u;
  u32 need = ctl[3];
  u32 base = ctl[4];
  u32 kstar = ctl[2];
  for (u32 t = threadIdx.x; t < T; t += blockDim.x) {
    int v = tie[t];
    u32 r = 0;
    for (u32 u = 0; u < T; ++u) r += (tie[u] < v) ? 1u : 0u;
    if (r < need) {
      sel[base + r] = v;
      comps[base + r] = ((u64)kstar << 32) | (u64)(0xFFFFFFFFu - (u32)v);
    }
  }
}

// Rank sort: comps tiled through LDS.
__global__ void k_rankdec(const u64* __restrict__ comps, const int* __restrict__ sel,
                          const float* __restrict__ bbox,
                          float4* __restrict__ props, float* __restrict__ areas) {
  __shared__ u64 tile[2048];
  int tid = threadIdx.x;
  int lane = tid & 63;
  int wave = tid >> 6;
  int base = (blockIdx.x * 4 + wave) * 8;
  u64 c0 = comps[base + 0], c1 = comps[base + 1], c2 = comps[base + 2], c3 = comps[base + 3];
  u64 c4 = comps[base + 4], c5 = comps[base + 5], c6 = comps[base + 6], c7 = comps[base + 7];
  int n0 = 0, n1 = 0, n2 = 0, n3 = 0, n4 = 0, n5 = 0, n6 = 0, n7 = 0;
  for (int t0 = 0; t0 < K_PRE; t0 += 2048) {
    int cnt = min(2048, K_PRE - t0);
    __syncthreads();
    for (int q = tid; q < cnt; q += 256) tile[q] = comps[t0 + q];
    __syncthreads();
    for (int q = lane; q < cnt; q += 64) {
      u64 v = tile[q];
      n0 += (v > c0); n1 += (v > c1); n2 += (v > c2); n3 += (v > c3);
      n4 += (v > c4); n5 += (v > c5); n6 += (v > c6); n7 += (v > c7);
    }
  }
  for (int off = 32; off; off >>= 1) {
    n0 += __shfl_xor(n0, off); n1 += __shfl_xor(n1, off);
    n2 += __shfl_xor(n2, off); n3 += __shfl_xor(n3, off);
    n4 += __shfl_xor(n4, off); n5 += __shfl_xor(n5, off);
    n6 += __shfl_xor(n6, off); n7 += __shfl_xor(n7, off);
  }
  int rk = n0;
  rk = (lane == 1) ? n1 : rk; rk = (lane == 2) ? n2 : rk;
  rk = (lane == 3) ? n3 : rk; rk = (lane == 4) ? n4 : rk;
  rk = (lane == 5) ? n5 : rk; rk = (lane == 6) ? n6 : rk;
  rk = (lane == 7) ? n7 : rk;
  if (lane < 8) {
    float4 box; float area; bool km;
    decode_box(bbox, sel[base + lane], &box, &area, &km);
    props[rk] = box;
    areas[rk] = area;
  }
}

// diag2/sub2 pair layout: entry (chunk c, half h, lane) = words
// {2c,2c+1} (diag) / {2c-2,2c-1} (sub2).
__device__ __forceinline__ int d2idx(int c, int h, int lane) {
  return ((c * 2 + h) * 64 + lane) * 2;
}

// IoU bitmask (R12 regions, plain stores).
__global__ void k_mask(const float4* __restrict__ props, const float* __restrict__ areas,
                       u64* __restrict__ mask, u64* __restrict__ diag2,
                       u64* __restrict__ sub2) {
#pragma clang fp contract(off)
  int x = blockIdx.x, y = blockIdx.y;
  int cx = x >> 1, cy = y >> 1;
  if (cy + 1 < cx || cy == cx + 1) return;
  __shared__ float4 bj[64];
  __shared__ float aj[64];
  int j0 = y * 64;
  bj[threadIdx.x] = props[j0 + threadIdx.x];
  aj[threadIdx.x] = areas[j0 + threadIdx.x];
  __syncthreads();
  int i = x * 64 + threadIdx.x;
  float4 bi = props[i];
  float ai = areas[i];
  u64 bits = 0;
  for (int jj = 0; jj < 64; ++jj) {
    int j = j0 + jj;
    float4 bb = bj[jj];
    float xx1 = fmaxf(bi.x, bb.x);
    float yy1 = fmaxf(bi.y, bb.y);
    float xx2 = fminf(bi.z, bb.z);
    float yy2 = fminf(bi.w, bb.w);
    float w = fmaxf(0.0f, (xx2 - xx1) + 1.0f);
    float h = fmaxf(0.0f, (yy2 - yy1) + 1.0f);
    float inter = w * h;
    float iou = inter / ((ai + aj[jj]) - inter);
    if ((iou > 0.7f) && (j < K_PRE)) bits |= (1ull << jj);
  }
  if (cy == cx)          diag2[d2idx(cx, x & 1, threadIdx.x) + (y & 1)] = bits;
  else if (cy == cx - 1) sub2[d2idx(cx, x & 1, threadIdx.x) + (y & 1)] = bits;
  else                   mask[(size_t)i * NWORD + y] = bits;
}

// Barrier without vmcnt drain (LDS-only cross-wave comms; in-flight
// global_load_lds stay outstanding across it).
#define NMS_BAR() asm volatile("s_waitcnt lgkmcnt(0)\n\ts_barrier" ::: "memory")

typedef __attribute__((address_space(1))) const u32* gas_p;
typedef __attribute__((address_space(3))) u32* las_p;
__device__ __forceinline__ void gll16(const u64* g, u64* l) {
  __builtin_amdgcn_global_load_lds((gas_p)g, (las_p)l, 16, 0, 0);
}

// Blocked greedy NMS v16 = R15 + ASM-FORCED far batch.
// R15's VGPR=28 proved the compiler still serialized the 8 far loads
// (load->OR->load->OR reusing 2 regs). One asm volatile block with 8
// back-to-back global_load_dwordx2 + a single s_waitcnt vmcnt(0) forces
// all 8 into ONE latency window; early-clobber outputs pin 16 VGPR pairs.
__global__ void __launch_bounds__(1024, 1) k_nms(const u64* __restrict__ mask,
                                                 const u64* __restrict__ diag2,
                                                 const u64* __restrict__ sub2,
                                                 const float4* __restrict__ props,
                                                 float* __restrict__ out) {
  __shared__ u64 rem[NWORD];
  __shared__ int keepb[K_POST];
  __shared__ int kept[2][128];
  __shared__ u64 dstage[2][2][64][2];   // [par][half][lane][pair]
  __shared__ u64 sstage[2][2][64][2];
  __shared__ int s_kk[2];
  __shared__ int s_nk;
  __shared__ int s_brk;
  int tid = threadIdx.x;
  int lane = tid & 63;
  int wave = tid >> 6;
  for (int w = tid; w < NWORD; w += 1024) {
    int base = w * 64;
    u64 v;
    if (base + 64 <= K_PRE) v = 0ull;
    else if (base >= K_PRE) v = ~0ull;
    else v = (~0ull) << (K_PRE - base);
    rem[w] = v;
  }
  if (tid == 0) { s_nk = 0; s_brk = 0; s_kk[0] = 0; s_kk[1] = 0; }
  if (wave == 0) {
    gll16(diag2 + d2idx(0, 0, lane), &dstage[0][0][0][0]);
    gll16(diag2 + d2idx(0, 1, lane), &dstage[0][1][0][0]);
    gll16(sub2 + d2idx(1, 0, lane), &sstage[1][0][0][0]);
    gll16(sub2 + d2idx(1, 1, lane), &sstage[1][1][0][0]);
  }
  __syncthreads();

  int nk = 0;

  for (int c = 0; c < NC; ++c) {
    if (s_brk) break;
    int par = c & 1;
    if (wave == 0) {
      int cn = min(c + 1, NC - 1);
      int cs = min(c + 2, NC - 1);
      gll16(diag2 + d2idx(cn, 0, lane), &dstage[cn & 1][0][0][0]);
      gll16(diag2 + d2idx(cn, 1, lane), &dstage[cn & 1][1][0][0]);
      gll16(sub2 + d2idx(cs, 0, lane), &sstage[cs & 1][0][0][0]);
      gll16(sub2 + d2idx(cs, 1, lane), &sstage[cs & 1][1][0][0]);
      asm volatile("s_waitcnt vmcnt(4)" ::: "memory");
      u64 dl0A = dstage[par][0][lane][0], dl1A = dstage[par][0][lane][1];
      u64 dh0A = dstage[par][1][lane][0], dh1A = dstage[par][1][lane][1];
      int ps = (c + 1) & 1;
      u64 sl0A = sstage[ps][0][lane][0], sl1A = sstage[ps][0][lane][1];
      u64 sh0A = sstage[ps][1][lane][0], sh1A = sstage[ps][1][lane][1];
      u64 w0 = ~rem[2 * c];
      u64 w1 = ~rem[2 * c + 1];
      u64 km0 = 0, km1 = 0;
      int nk0 = nk;
      while (w0 != 0ull && nk < K_POST) {
        int j = (int)__builtin_ctzll(w0);
        u64 sup = __ballot((int)((dl0A >> j) & 1ull));
        km0 |= (1ull << j);
        nk++;
        w0 &= ~sup;        // includes bit j (diag self-bit always set)
      }
      if (km0) w1 &= ~__ballot((int)((dh0A & km0) != 0ull));  // bulk hi-mask
      while (w1 != 0ull && nk < K_POST) {
        int j = (int)__builtin_ctzll(w1);
        u64 sup = __ballot((int)((dh1A >> j) & 1ull));
        km1 |= (1ull << j);
        nk++;
        w1 &= ~sup;        // includes bit j
      }
      // lane-parallel emit (keeps are in increasing index order)
      int ncnt0 = __popcll(km0);
      u64 below = (1ull << lane) - 1ull;
      if ((km0 >> lane) & 1ull) {
        int pos = nk0 + __popcll(km0 & below);
        int idx = (c << 7) | lane;
        keepb[pos] = idx;
        kept[par][pos - nk0] = idx;
      }
      if ((km1 >> lane) & 1ull) {
        int pos = nk0 + ncnt0 + __popcll(km1 & below);
        int idx = (c << 7) | 64 | lane;
        keepb[pos] = idx;
        kept[par][pos - nk0] = idx;
      }
      if (c + 1 < NC) {
        int plo = (int)((((sl0A & km0) | (sl1A & km1)) != 0ull) ? 1 : 0);
        int phi = (int)((((sh0A & km0) | (sh1A & km1)) != 0ull) ? 1 : 0);
        u64 vlo = __ballot(plo);
        u64 vhi = __ballot(phi);
        if (lane == 0) {
          if (vlo) atomicOr((unsigned long long*)&rem[2 * c + 2], (unsigned long long)vlo);
          if (vhi) atomicOr((unsigned long long*)&rem[2 * c + 3], (unsigned long long)vhi);
        }
      }
      if (lane == 0) { s_kk[par] = nk - nk0; s_nk = nk; s_brk = (nk >= K_POST) ? 1 : 0; }
    } else if (c >= 1) {
      int kkp = s_kk[par ^ 1];
      const int* kb = &kept[par ^ 1][0];
      int wv = wave - 1;              // 0..14
      int seg = wv % 3;               // wave-uniform segment
      int q0 = wv / 3;                // 0..4; rows q0, q0+5, ..., q0+35
      int w = 2 * c + 2 + seg * 64 + lane;
      if (kkp > q0 && w < NWORD) {
        int m = kkp - 1;
        const u64* p0 = mask + (size_t)kb[q0] * NWORD + w;
        const u64* p1 = mask + (size_t)kb[min(q0 + 5, m)] * NWORD + w;
        const u64* p2 = mask + (size_t)kb[min(q0 + 10, m)] * NWORD + w;
        const u64* p3 = mask + (size_t)kb[min(q0 + 15, m)] * NWORD + w;
        const u64* p4 = mask + (size_t)kb[min(q0 + 20, m)] * NWORD + w;
        const u64* p5 = mask + (size_t)kb[min(q0 + 25, m)] * NWORD + w;
        const u64* p6 = mask + (size_t)kb[min(q0 + 30, m)] * NWORD + w;
        const u64* p7 = mask + (size_t)kb[min(q0 + 35, m)] * NWORD + w;
        u64 fp0, fp1, fp2, fp3, fp4, fp5, fp6, fp7;
        asm volatile(
          "global_load_dwordx2 %0, %8, off\n\t"
          "global_load_dwordx2 %1, %9, off\n\t"
          "global_load_dwordx2 %2, %10, off\n\t"
          "global_load_dwordx2 %3, %11, off\n\t"
          "global_load_dwordx2 %4, %12, off\n\t"
          "global_load_dwordx2 %5, %13, off\n\t"
          "global_load_dwordx2 %6, %14, off\n\t"
          "global_load_dwordx2 %7, %15, off\n\t"
          "s_waitcnt vmcnt(0)"
          : "=&v"(fp0), "=&v"(fp1), "=&v"(fp2), "=&v"(fp3),
            "=&v"(fp4), "=&v"(fp5), "=&v"(fp6), "=&v"(fp7)
          : "v"(p0), "v"(p1), "v"(p2), "v"(p3),
            "v"(p4), "v"(p5), "v"(p6), "v"(p7)
          : "memory");
        u64 v = (fp0 | fp1) | (fp2 | fp3) | ((fp4 | fp5) | (fp6 | fp7));
        for (int q = q0 + 40; q < kkp; q += 5)   // rare overflow
          v |= mask[(size_t)kb[q] * NWORD + w];
        if (v) atomicOr((unsigned long long*)&rem[w], (unsigned long long)v);
      }
    }
    NMS_BAR();
  }
  __syncthreads();
  int fnk = s_nk;
  for (int t = tid; t < K_POST; t += 1024) {
    int kidx = (t < fnk) ? keepb[t] : 0;   // exhausted: argmax over -inf -> 0
    float4 b = props[kidx];
    out[t * 5 + 0] = 0.0f;
    out[t * 5 + 1] = b.x;
    out[t * 5 + 2] = b.y;
    out[t * 5 + 3] = b.z;
    out[t * 5 + 4] = b.w;
  }
}

extern "C" void kernel_launch(void* const* d_in, const int* in_sizes, int n_in,
                              void* d_out, int out_size, void* d_ws, size_t ws_size,
                              hipStream_t stream) {
  const float* cls  = (const float*)d_in[0];
  const float* bbox = (const float*)d_in[1];
  float* out = (float*)d_out;
  char* ws = (char*)d_ws;

  // Layout. mask [0,18096128) overlays keys/ctl/hist/sel/tie (dead before k_mask).
  u64* mask    = (u64*)ws;                      // u64[12032*188]
  u32* keys    = (u32*)ws;                      // [0, 9437184)
  u32* ctl     = (u32*)(ws + 9437184);
  u32* hist    = (u32*)(ws + 9437248);
  int* sel     = (int*)(ws + 9438464);
  int* tie     = (int*)(ws + 9486592);
  u64* comps   = (u64*)(ws + 18096128);         // +96256
  float4* props= (float4*)(ws + 18240512);      // +192512
  float* areas = (float*)(ws + 18433024);       // +48128
  u64* diag2   = (u64*)(ws + 18481152);         // +192512
  u64* sub2    = (u64*)(ws + 18673664);         // +192512 -> 18866176 total

  k_scores<<<dim3((N_ANCH + 255) / 256), dim3(256), 0, stream>>>(cls, bbox, keys, ctl, hist);
  const int shifts[4] = {24, 16, 8, 0};
  for (int s = 0; s < 4; ++s)
    k_histscan<<<dim3(256), dim3(1024), 0, stream>>>(keys, ctl, hist, shifts[s], s);
  k_collect<<<dim3(256), dim3(1024), 0, stream>>>(keys, ctl, sel, tie, comps);
  k_tiepick<<<dim3(1), dim3(256), 0, stream>>>(ctl, tie, sel, comps);
  k_rankdec<<<dim3(375), dim3(256), 0, stream>>>(comps, sel, bbox, props, areas);
  k_mask<<<dim3(188, 188), dim3(64), 0, stream>>>(props, areas, mask, diag2, sub2);
  k_nms<<<dim3(1), dim3(1024), 0, stream>>>(mask, diag2, sub2, props, out);
}